// Round 1
// baseline (295.974 us; speedup 1.0000x reference)
//
#include <hip/hip_runtime.h>

#define NN 50000
#define NE 1600000

// Workspace layout (floats): deg[NN] | dinv[NN] | A[NN*32] | Mz[1024] | Mh[1024] | cz[32] | ch[32]
// Total = 34*NN + 2112 floats ~= 6.81 MB.

// Fold Wz@Lz_w[:32,:] -> Mz, bias -> cz (same for h gate). One block, 1024 threads.
__global__ void k_prep(const float* __restrict__ Wz, const float* __restrict__ Lzw,
                       const float* __restrict__ bz, const float* __restrict__ Lzb,
                       const float* __restrict__ Wh, const float* __restrict__ Lhw,
                       const float* __restrict__ bh, const float* __restrict__ Lhb,
                       float* __restrict__ Mz, float* __restrict__ Mh,
                       float* __restrict__ cz, float* __restrict__ ch) {
    int t = threadIdx.x;
    int i = t >> 5, j = t & 31;
    float sz = 0.f, sh = 0.f;
#pragma unroll
    for (int k = 0; k < 32; ++k) {
        sz += Wz[i * 32 + k] * Lzw[k * 32 + j];
        sh += Wh[i * 32 + k] * Lhw[k * 32 + j];
    }
    Mz[i * 32 + j] = sz;
    Mh[i * 32 + j] = sh;
    if (t < 32) {
        float az = Lzb[t], ah = Lhb[t];
        for (int k = 0; k < 32; ++k) {
            az += bz[k] * Lzw[k * 32 + t];
            ah += bh[k] * Lhw[k * 32 + t];
        }
        cz[t] = az;
        ch[t] = ah;
    }
}

// deg[n] = 1.0 (self-loop weight); ws is poisoned, must init every call.
__global__ void k_deginit(float* __restrict__ deg) {
    int n = blockIdx.x * blockDim.x + threadIdx.x;
    if (n < NN) deg[n] = 1.0f;
}

// deg[dst] += ew  (edge_index row 1 = dst)
__global__ void k_deg(const int* __restrict__ ei, const float* __restrict__ ew,
                      float* __restrict__ deg) {
    int e = blockIdx.x * blockDim.x + threadIdx.x;
    if (e < NE) atomicAdd(&deg[ei[NE + e]], ew[e]);
}

__global__ void k_dinv(const float* __restrict__ deg, float* __restrict__ dinv) {
    int n = blockIdx.x * blockDim.x + threadIdx.x;
    if (n < NN) dinv[n] = rsqrtf(deg[n]);  // deg >= 1 always (self-loop)
}

// A[n][:] = dinv[n]^2 * x[n][:]  (self-loop term), float4-vectorized: NN*8 threads
__global__ void k_ainit(const float* __restrict__ x, const float* __restrict__ dinv,
                        float* __restrict__ A) {
    int i = blockIdx.x * blockDim.x + threadIdx.x;
    if (i < NN * 8) {
        float d = dinv[i >> 3];
        float s = d * d;
        float4 v = ((const float4*)x)[i];
        ((float4*)A)[i] = make_float4(s * v.x, s * v.y, s * v.z, s * v.w);
    }
}

// A[dst][f] += dinv[src]*ew*dinv[dst] * x[src][f]
// One thread per (edge, feature): 32 consecutive lanes share one edge ->
// edge-metadata loads broadcast, x[src*32+f] gather is a coalesced 128B line.
__global__ void k_edge(const int* __restrict__ ei, const float* __restrict__ ew,
                       const float* __restrict__ x, const float* __restrict__ dinv,
                       float* __restrict__ A) {
    unsigned tid = blockIdx.x * blockDim.x + threadIdx.x;
    unsigned stride = gridDim.x * blockDim.x;
    const unsigned total = (unsigned)NE * 32u;
    for (unsigned t = tid; t < total; t += stride) {
        unsigned e = t >> 5, f = t & 31;
        int s = ei[e];
        int d = ei[NE + e];
        float coef = dinv[s] * ew[e] * dinv[d];
        atomicAdd(&A[(unsigned)d * 32u + f], coef * x[(unsigned)s * 32u + f]);
    }
}

// Per-node epilogue: two 32x32 matvecs (gates), relu, 32x16 matvec, softmax16.
__global__ __launch_bounds__(256) void k_dense(
        const float* __restrict__ A, const float* __restrict__ Mz,
        const float* __restrict__ Mh, const float* __restrict__ cz,
        const float* __restrict__ ch, const float* __restrict__ Wout,
        const float* __restrict__ bout, float* __restrict__ out) {
    __shared__ float sMz[1024], sMh[1024], sW[512], scz[32], sch[32], sb[16];
    for (int i = threadIdx.x; i < 1024; i += 256) {
        sMz[i] = Mz[i];
        sMh[i] = Mh[i];
    }
    for (int i = threadIdx.x; i < 512; i += 256) sW[i] = Wout[i];
    if (threadIdx.x < 32) {
        scz[threadIdx.x] = cz[threadIdx.x];
        sch[threadIdx.x] = ch[threadIdx.x];
    }
    if (threadIdx.x < 16) sb[threadIdx.x] = bout[threadIdx.x];
    __syncthreads();

    int n = blockIdx.x * 256 + threadIdx.x;
    if (n >= NN) return;

    float a[32];
    const float4* A4 = (const float4*)(A + (size_t)n * 32);
#pragma unroll
    for (int q = 0; q < 8; ++q) {
        float4 v = A4[q];
        a[q * 4 + 0] = v.x; a[q * 4 + 1] = v.y; a[q * 4 + 2] = v.z; a[q * 4 + 3] = v.w;
    }

    float h[32];
#pragma unroll 4
    for (int j = 0; j < 32; ++j) {
        float z = scz[j], g = sch[j];
#pragma unroll
        for (int k = 0; k < 32; ++k) {
            z += a[k] * sMz[k * 32 + j];
            g += a[k] * sMh[k * 32 + j];
        }
        z = 1.0f / (1.0f + expf(-z));       // sigmoid
        g = tanhf(g);
        float hv = (1.0f - z) * g;          // H = Z*0 + (1-Z)*H_tilde
        h[j] = hv > 0.f ? hv : 0.f;         // relu fused
    }

    float lo[16];
    float mx = -1e30f;
#pragma unroll
    for (int c = 0; c < 16; ++c) {
        float l = sb[c];
#pragma unroll
        for (int j = 0; j < 32; ++j) l += h[j] * sW[j * 16 + c];
        lo[c] = l;
        mx = fmaxf(mx, l);
    }
    float sum = 0.f;
#pragma unroll
    for (int c = 0; c < 16; ++c) {
        lo[c] = expf(lo[c] - mx);
        sum += lo[c];
    }
    float inv = 1.0f / sum;
    float4* o4 = (float4*)(out + (size_t)n * 16);
#pragma unroll
    for (int q = 0; q < 4; ++q)
        o4[q] = make_float4(lo[q * 4 + 0] * inv, lo[q * 4 + 1] * inv,
                            lo[q * 4 + 2] * inv, lo[q * 4 + 3] * inv);
}

extern "C" void kernel_launch(void* const* d_in, const int* in_sizes, int n_in,
                              void* d_out, int out_size, void* d_ws, size_t ws_size,
                              hipStream_t stream) {
    const float* x    = (const float*)d_in[0];
    const int*   ei   = (const int*)d_in[1];   // [2, E] int32 (harness converts int64)
    const float* ew   = (const float*)d_in[2];
    const float* Wz   = (const float*)d_in[3];
    const float* bz   = (const float*)d_in[4];
    // d_in[5], d_in[6] (Wr, br) are dead: R gate multiplies H0 = 0.
    const float* Wh   = (const float*)d_in[7];
    const float* bh   = (const float*)d_in[8];
    const float* Lzw  = (const float*)d_in[9];
    const float* Lzb  = (const float*)d_in[10];
    // d_in[11], d_in[12] (Lr) dead.
    const float* Lhw  = (const float*)d_in[13];
    const float* Lhb  = (const float*)d_in[14];
    const float* Wout = (const float*)d_in[15];
    const float* bout = (const float*)d_in[16];
    float* out = (float*)d_out;

    float* ws   = (float*)d_ws;
    float* deg  = ws;                 // NN
    float* dinv = ws + NN;            // NN
    float* A    = ws + 2 * NN;        // NN*32
    float* Mz   = A + (size_t)NN * 32;  // 1024
    float* Mh   = Mz + 1024;          // 1024
    float* cz   = Mh + 1024;          // 32
    float* ch   = cz + 32;            // 32

    k_prep<<<1, 1024, 0, stream>>>(Wz, Lzw, bz, Lzb, Wh, Lhw, bh, Lhb, Mz, Mh, cz, ch);
    k_deginit<<<(NN + 255) / 256, 256, 0, stream>>>(deg);
    k_deg<<<(NE + 255) / 256, 256, 0, stream>>>(ei, ew, deg);
    k_dinv<<<(NN + 255) / 256, 256, 0, stream>>>(deg, dinv);
    k_ainit<<<(NN * 8 + 255) / 256, 256, 0, stream>>>(x, dinv, A);
    k_edge<<<8192, 256, 0, stream>>>(ei, ew, x, dinv, A);
    k_dense<<<(NN + 255) / 256, 256, 0, stream>>>(A, Mz, Mh, cz, ch, Wout, bout, out);
}